// Round 1
// baseline (453.188 us; speedup 1.0000x reference)
//
#include <hip/hip_runtime.h>
#include <math.h>

#define NQ   12
#define NL   4
#define DIMS 4096
#define NT   256

using cplx = float2;

__device__ __forceinline__ cplx cmul(cplx a, cplx b) {
    return make_float2(fmaf(a.x, b.x, -a.y * b.y), fmaf(a.x, b.y, a.y * b.x));
}
__device__ __forceinline__ cplx cmadd(cplx a, cplx b, cplx acc) {
    acc.x = fmaf(a.x, b.x, fmaf(-a.y, b.y, acc.x));
    acc.y = fmaf(a.x, b.y, fmaf(a.y, b.x, acc.y));
    return acc;
}
// C = A * B (2x2 complex, row-major m00 m01 m10 m11)
__device__ __forceinline__ void mm2(const cplx* A, const cplx* B, cplx* C) {
    C[0] = cmadd(A[1], B[2], cmul(A[0], B[0]));
    C[1] = cmadd(A[1], B[3], cmul(A[0], B[1]));
    C[2] = cmadd(A[3], B[2], cmul(A[2], B[0]));
    C[3] = cmadd(A[3], B[3], cmul(A[2], B[1]));
}

// PennyLane Rot(phi, theta, omega) = RZ(omega) RY(theta) RZ(phi)
__device__ __forceinline__ void rotmat(float phi, float th, float om, cplx* M) {
    float ct, st_, ca, sa, cd, sd;
    sincosf(0.5f * th, &st_, &ct);
    sincosf(0.5f * (phi + om), &sa, &ca);
    sincosf(0.5f * (phi - om), &sd, &cd);
    M[0] = make_float2(ct * ca, -ct * sa);
    M[1] = make_float2(-st_ * cd, -st_ * sd);
    M[2] = make_float2(st_ * cd, -st_ * sd);
    M[3] = make_float2(ct * ca, ct * sa);
}

__global__ __launch_bounds__(NT) void qsim_kernel(
    const float* __restrict__ x,      // (B, 4, NQ)
    const float* __restrict__ prot,   // (NL, NQ, 3)
    const float* __restrict__ penta,  // (NL, NQ, 3)
    float* __restrict__ out)          // (B, NQ)
{
    __shared__ cplx st[DIMS];
    __shared__ cplx encM[NQ][4];
    __shared__ cplx FM[NL * NQ][4];   // fused Rot*ENC per layer,qubit
    __shared__ cplx CM[NL * NQ][4];   // CRot target matrices
    __shared__ float zred[NT / 64][NQ];

    const int tid = threadIdx.x;
    const int b   = blockIdx.x;

    // ---- init state |0..0>
    for (int i = tid; i < DIMS; i += NT)
        st[i] = make_float2(i == 0 ? 1.0f : 0.0f, 0.0f);

    // ---- per-sample fused encoding matrices: ENC = RY(x3) RZ(x2) RX(x1) RY(x0)
    if (tid < NQ) {
        const int q = tid;
        const float* xb = x + (size_t)b * 4 * NQ;
        const float t0 = xb[q], t1 = xb[NQ + q], t2 = xb[2 * NQ + q], t3 = xb[3 * NQ + q];
        float c, s;
        sincosf(0.5f * t0, &s, &c);
        cplx R0[4] = {{c, 0.f}, {-s, 0.f}, {s, 0.f}, {c, 0.f}};       // RY(x0)
        sincosf(0.5f * t1, &s, &c);
        cplx R1[4] = {{c, 0.f}, {0.f, -s}, {0.f, -s}, {c, 0.f}};      // RX(x1)
        sincosf(0.5f * t2, &s, &c);
        cplx R2[4] = {{c, -s}, {0.f, 0.f}, {0.f, 0.f}, {c, s}};       // RZ(x2)
        sincosf(0.5f * t3, &s, &c);
        cplx R3[4] = {{c, 0.f}, {-s, 0.f}, {s, 0.f}, {c, 0.f}};       // RY(x3)
        cplx T1[4], T2[4], E[4];
        mm2(R1, R0, T1);
        mm2(R2, T1, T2);
        mm2(R3, T2, E);
        #pragma unroll
        for (int i = 0; i < 4; ++i) encM[q][i] = E[i];
    }
    // ---- CRot matrices (independent of encoding)
    if (tid >= 64 && tid < 64 + NL * NQ) {
        const int idx = tid - 64;
        const float* p = penta + idx * 3;
        cplx M[4];
        rotmat(p[0], p[1], p[2], M);
        #pragma unroll
        for (int i = 0; i < 4; ++i) CM[idx][i] = M[i];
    }
    __syncthreads();
    // ---- fused F = Rot * ENC
    if (tid < NL * NQ) {
        const int q = tid % NQ;
        const float* p = prot + tid * 3;
        cplx R[4], Fm[4];
        rotmat(p[0], p[1], p[2], R);
        mm2(R, encM[q], Fm);
        #pragma unroll
        for (int i = 0; i < 4; ++i) FM[tid][i] = Fm[i];
    }
    __syncthreads();

    // ---- circuit
    for (int l = 0; l < NL; ++l) {
        // 12 fused 1q gates (ENC+Rot), wire q -> bit (11-q)
        for (int q = 0; q < NQ; ++q) {
            cplx M0 = FM[l * NQ + q][0], M1 = FM[l * NQ + q][1];
            cplx M2 = FM[l * NQ + q][2], M3 = FM[l * NQ + q][3];
            const int k = 11 - q;
            const int mask = (1 << k) - 1;
            for (int p = tid; p < DIMS / 2; p += NT) {
                const int i0 = ((p & ~mask) << 1) | (p & mask);
                const int i1 = i0 | (1 << k);
                cplx v0 = st[i0], v1 = st[i1];
                cplx n0 = cmadd(M1, v1, cmul(M0, v0));
                cplx n1 = cmadd(M3, v1, cmul(M2, v0));
                st[i0] = n0;
                st[i1] = n1;
            }
            __syncthreads();
        }
        // 12 CRot gates: control wire q (bit 11-q), target wire (q+1)%12
        for (int q = 0; q < NQ; ++q) {
            cplx M0 = CM[l * NQ + q][0], M1 = CM[l * NQ + q][1];
            cplx M2 = CM[l * NQ + q][2], M3 = CM[l * NQ + q][3];
            const int kc = 11 - q;
            const int kt = 11 - ((q + 1) % NQ);
            const int a = kc < kt ? kc : kt;
            const int bb = kc < kt ? kt : kc;
            const int ma = (1 << a) - 1;
            const int mb = (1 << bb) - 1;
            for (int p = tid; p < DIMS / 4; p += NT) {
                int i = ((p & ~ma) << 1) | (p & ma);   // insert 0 at bit a
                i = ((i & ~mb) << 1) | (i & mb);       // insert 0 at bit bb
                i |= (1 << kc);                        // control = 1
                const int i1 = i | (1 << kt);          // i has target bit 0
                cplx v0 = st[i], v1 = st[i1];
                cplx n0 = cmadd(M1, v1, cmul(M0, v0));
                cplx n1 = cmadd(M3, v1, cmul(M2, v0));
                st[i] = n0;
                st[i1] = n1;
            }
            __syncthreads();
        }
    }

    // ---- measurement: z_i = sum |amp|^2 * (1 - 2*bit_{11-i})
    float z[NQ];
    #pragma unroll
    for (int i = 0; i < NQ; ++i) z[i] = 0.0f;
    for (int idx = tid; idx < DIMS; idx += NT) {
        cplx v = st[idx];
        float pr = fmaf(v.x, v.x, v.y * v.y);
        int pbits = __float_as_int(pr);
        #pragma unroll
        for (int i = 0; i < NQ; ++i) {
            // bit (11-i) of idx moved to the sign position
            int sgn = (idx << (20 + i)) & 0x80000000;
            z[i] += __int_as_float(pbits ^ sgn);
        }
    }
    #pragma unroll
    for (int i = 0; i < NQ; ++i) {
        float v = z[i];
        for (int off = 32; off > 0; off >>= 1) v += __shfl_down(v, off);
        z[i] = v;
    }
    const int wave = tid >> 6;
    if ((tid & 63) == 0) {
        #pragma unroll
        for (int i = 0; i < NQ; ++i) zred[wave][i] = z[i];
    }
    __syncthreads();
    if (tid < NQ) {
        float v = zred[0][tid] + zred[1][tid] + zred[2][tid] + zred[3][tid];
        out[(size_t)b * NQ + tid] = v;
    }
}

extern "C" void kernel_launch(void* const* d_in, const int* in_sizes, int n_in,
                              void* d_out, int out_size, void* d_ws, size_t ws_size,
                              hipStream_t stream) {
    const float* x     = (const float*)d_in[0];
    const float* prot  = (const float*)d_in[1];
    const float* penta = (const float*)d_in[2];
    float* out = (float*)d_out;
    const int B = in_sizes[0] / (4 * NQ);   // 4096
    qsim_kernel<<<B, NT, 0, stream>>>(x, prot, penta, out);
}

// Round 2
// 354.670 us; speedup vs baseline: 1.2778x; 1.2778x over previous
//
#include <hip/hip_runtime.h>
#include <math.h>

#define NQ   12
#define NL   4
#define DIMS 4096
#define NT   256
#define AMPS 16   // per-thread amplitudes (local bits [3:0])

using cplx = float2;

__device__ __forceinline__ cplx cmul(cplx a, cplx b) {
    return make_float2(fmaf(a.x, b.x, -a.y * b.y), fmaf(a.x, b.y, a.y * b.x));
}
__device__ __forceinline__ cplx cmadd(cplx a, cplx b, cplx acc) {
    acc.x = fmaf(a.x, b.x, fmaf(-a.y, b.y, acc.x));
    acc.y = fmaf(a.x, b.y, fmaf(a.y, b.x, acc.y));
    return acc;
}
__device__ __forceinline__ void mm2(const cplx* A, const cplx* B, cplx* C) {
    C[0] = cmadd(A[1], B[2], cmul(A[0], B[0]));
    C[1] = cmadd(A[1], B[3], cmul(A[0], B[1]));
    C[2] = cmadd(A[3], B[2], cmul(A[2], B[0]));
    C[3] = cmadd(A[3], B[3], cmul(A[2], B[1]));
}
// PennyLane Rot(phi, theta, omega) = RZ(omega) RY(theta) RZ(phi)
__device__ __forceinline__ void rotmat(float phi, float th, float om, cplx* M) {
    float ct, st_, ca, sa, cd, sd;
    sincosf(0.5f * th, &st_, &ct);
    sincosf(0.5f * (phi + om), &sa, &ca);
    sincosf(0.5f * (phi - om), &sd, &cd);
    M[0] = make_float2(ct * ca, -ct * sa);
    M[1] = make_float2(-st_ * cd, -st_ * sd);
    M[2] = make_float2(st_ * cd, -st_ * sd);
    M[3] = make_float2(ct * ca, ct * sa);
}

__device__ __forceinline__ void ldmat(const cplx* m, cplx& M0, cplx& M1, cplx& M2, cplx& M3) {
    M0 = m[0]; M1 = m[1]; M2 = m[2]; M3 = m[3];
}
// For a pair (v0: bit=0, v1: bit=1): n_self = Mx * v_self + My * v_partner.
// lo lane: n0 = M0 v0 + M1 v1 -> Mx=M0, My=M1 ; hi lane: n1 = M2 v0 + M3 v1 -> Mx=M3, My=M2.
__device__ __forceinline__ void selmat(bool ctrl, bool hi,
                                       cplx M0, cplx M1, cplx M2, cplx M3,
                                       cplx& Mx, cplx& My) {
    Mx = hi ? M3 : M0;
    My = hi ? M2 : M1;
    if (!ctrl) { Mx = make_float2(1.f, 0.f); My = make_float2(0.f, 0.f); }
}

// ---- in-register gate on local bit K (0..3)
template<int K>
__device__ __forceinline__ void g1q_local(cplx* s, cplx M0, cplx M1, cplx M2, cplx M3) {
    #pragma unroll
    for (int j = 0; j < AMPS; ++j) {
        if ((j >> K) & 1) continue;
        const int i1 = j | (1 << K);
        cplx v0 = s[j], v1 = s[i1];
        s[j]  = cmadd(M1, v1, cmul(M0, v0));
        s[i1] = cmadd(M3, v1, cmul(M2, v0));
    }
}
// ---- shuffle gate on lane bit (mask LM in {1..32}), uniform per-thread Mx/My already selected
template<int LM>
__device__ __forceinline__ void lane_core(cplx* s, cplx Mx, cplx My) {
    #pragma unroll
    for (int j0 = 0; j0 < AMPS; j0 += 8) {
        cplx pv[8];
        #pragma unroll
        for (int j = 0; j < 8; ++j) {
            pv[j].x = __shfl_xor(s[j0 + j].x, LM, 64);
            pv[j].y = __shfl_xor(s[j0 + j].y, LM, 64);
        }
        #pragma unroll
        for (int j = 0; j < 8; ++j)
            s[j0 + j] = cmadd(My, pv[j], cmul(Mx, s[j0 + j]));
    }
}
// ---- cross-wave gate via LDS, partner = tid ^ PO (PO = 64 or 128), all 16 amps
template<int PO>
__device__ __forceinline__ void g_wave_full(cplx* s, cplx Mx, cplx My, cplx* xbuf, int tid) {
    #pragma unroll
    for (int r = 0; r < 2; ++r) {
        __syncthreads();
        #pragma unroll
        for (int j = 0; j < 8; ++j) xbuf[j * NT + tid] = s[r * 8 + j];
        __syncthreads();
        #pragma unroll
        for (int j = 0; j < 8; ++j) {
            cplx pv = xbuf[j * NT + (tid ^ PO)];
            s[r * 8 + j] = cmadd(My, pv, cmul(Mx, s[r * 8 + j]));
        }
    }
}
// ---- CRot with control & target both local: CB control bit, TB target bit
template<int CB, int TB>
__device__ __forceinline__ void crot_local(cplx* s, cplx M0, cplx M1, cplx M2, cplx M3) {
    #pragma unroll
    for (int j = 0; j < AMPS; ++j) {
        if (((j >> CB) & 1) && !((j >> TB) & 1)) {
            const int i1 = j | (1 << TB);
            cplx v0 = s[j], v1 = s[i1];
            s[j]  = cmadd(M1, v1, cmul(M0, v0));
            s[i1] = cmadd(M3, v1, cmul(M2, v0));
        }
    }
}

__global__ __launch_bounds__(NT, 4) void qsim_kernel(
    const float* __restrict__ x,      // (B, 4, NQ)
    const float* __restrict__ prot,   // (NL, NQ, 3)
    const float* __restrict__ penta,  // (NL, NQ, 3)
    float* __restrict__ out)          // (B, NQ)
{
    __shared__ cplx xbuf[8 * NT];          // 16 KB exchange buffer
    __shared__ cplx encM[NQ][4];
    __shared__ cplx FM[NL * NQ][4];        // fused Rot*ENC
    __shared__ cplx CMt[NL * NQ][4];       // CRot target matrices
    __shared__ float zred[4][NQ];

    const int tid  = threadIdx.x;
    const int lane = tid & 63;
    const int b    = blockIdx.x;

    // ---- matrix setup (same scheme as validated round-1 kernel)
    if (tid < NQ) {
        const int q = tid;
        const float* xb = x + (size_t)b * 4 * NQ;
        const float t0 = xb[q], t1 = xb[NQ + q], t2 = xb[2 * NQ + q], t3 = xb[3 * NQ + q];
        float c, s;
        sincosf(0.5f * t0, &s, &c);
        cplx R0[4] = {{c, 0.f}, {-s, 0.f}, {s, 0.f}, {c, 0.f}};       // RY(x0)
        sincosf(0.5f * t1, &s, &c);
        cplx R1[4] = {{c, 0.f}, {0.f, -s}, {0.f, -s}, {c, 0.f}};      // RX(x1)
        sincosf(0.5f * t2, &s, &c);
        cplx R2[4] = {{c, -s}, {0.f, 0.f}, {0.f, 0.f}, {c, s}};       // RZ(x2)
        sincosf(0.5f * t3, &s, &c);
        cplx R3[4] = {{c, 0.f}, {-s, 0.f}, {s, 0.f}, {c, 0.f}};       // RY(x3)
        cplx T1[4], T2[4], E[4];
        mm2(R1, R0, T1);
        mm2(R2, T1, T2);
        mm2(R3, T2, E);
        #pragma unroll
        for (int i = 0; i < 4; ++i) encM[q][i] = E[i];
    }
    if (tid >= 64 && tid < 64 + NL * NQ) {
        const int idx = tid - 64;
        const float* p = penta + idx * 3;
        cplx M[4];
        rotmat(p[0], p[1], p[2], M);
        #pragma unroll
        for (int i = 0; i < 4; ++i) CMt[idx][i] = M[i];
    }
    __syncthreads();
    if (tid < NL * NQ) {
        const int q = tid % NQ;
        const float* p = prot + tid * 3;
        cplx R[4], Fm[4];
        rotmat(p[0], p[1], p[2], R);
        mm2(R, encM[q], Fm);
        #pragma unroll
        for (int i = 0; i < 4; ++i) FM[tid][i] = Fm[i];
    }
    __syncthreads();

    // ---- state in registers: amp index = (tid<<4) | j
    cplx s[AMPS];
    #pragma unroll
    for (int j = 0; j < AMPS; ++j) s[j] = make_float2(0.f, 0.f);
    if (tid == 0) s[0] = make_float2(1.f, 0.f);

    cplx M0, M1, M2, M3, Mx, My;

    for (int l = 0; l < NL; ++l) {
        const cplx* FMl = &FM[l * NQ][0];
        const cplx* CMl = &CMt[l * NQ][0];

        // ===== fused 1q gates (ENC+Rot), qubit q -> state bit 11-q =====
        // q0: bit 11 (wave bit 1, partner tid^128)
        ldmat(FMl + 0 * 4, M0, M1, M2, M3);
        selmat(true, tid & 128, M0, M1, M2, M3, Mx, My);
        g_wave_full<128>(s, Mx, My, xbuf, tid);
        // q1: bit 10 (wave bit 0, partner tid^64)
        ldmat(FMl + 1 * 4, M0, M1, M2, M3);
        selmat(true, tid & 64, M0, M1, M2, M3, Mx, My);
        g_wave_full<64>(s, Mx, My, xbuf, tid);
        // q2..q7: lane bits 5..0
        ldmat(FMl + 2 * 4, M0, M1, M2, M3);
        selmat(true, lane & 32, M0, M1, M2, M3, Mx, My);
        lane_core<32>(s, Mx, My);
        ldmat(FMl + 3 * 4, M0, M1, M2, M3);
        selmat(true, lane & 16, M0, M1, M2, M3, Mx, My);
        lane_core<16>(s, Mx, My);
        ldmat(FMl + 4 * 4, M0, M1, M2, M3);
        selmat(true, lane & 8, M0, M1, M2, M3, Mx, My);
        lane_core<8>(s, Mx, My);
        ldmat(FMl + 5 * 4, M0, M1, M2, M3);
        selmat(true, lane & 4, M0, M1, M2, M3, Mx, My);
        lane_core<4>(s, Mx, My);
        ldmat(FMl + 6 * 4, M0, M1, M2, M3);
        selmat(true, lane & 2, M0, M1, M2, M3, Mx, My);
        lane_core<2>(s, Mx, My);
        ldmat(FMl + 7 * 4, M0, M1, M2, M3);
        selmat(true, lane & 1, M0, M1, M2, M3, Mx, My);
        lane_core<1>(s, Mx, My);
        // q8..q11: local bits 3..0
        ldmat(FMl + 8 * 4, M0, M1, M2, M3);  g1q_local<3>(s, M0, M1, M2, M3);
        ldmat(FMl + 9 * 4, M0, M1, M2, M3);  g1q_local<2>(s, M0, M1, M2, M3);
        ldmat(FMl + 10 * 4, M0, M1, M2, M3); g1q_local<1>(s, M0, M1, M2, M3);
        ldmat(FMl + 11 * 4, M0, M1, M2, M3); g1q_local<0>(s, M0, M1, M2, M3);

        // ===== CRot ring, strict order q=0..11 =====
        // q0: c=bit11 (tid&128), t=bit10 (partner tid^64) — wave-uniform active set
        {
            ldmat(CMl + 0 * 4, M0, M1, M2, M3);
            const bool act = (tid & 128) != 0;
            selmat(true, tid & 64, M0, M1, M2, M3, Mx, My);
            #pragma unroll
            for (int r = 0; r < 2; ++r) {
                __syncthreads();
                if (act) {
                    #pragma unroll
                    for (int j = 0; j < 8; ++j) xbuf[j * NT + tid] = s[r * 8 + j];
                }
                __syncthreads();
                if (act) {
                    #pragma unroll
                    for (int j = 0; j < 8; ++j) {
                        cplx pv = xbuf[j * NT + (tid ^ 64)];
                        s[r * 8 + j] = cmadd(My, pv, cmul(Mx, s[r * 8 + j]));
                    }
                }
            }
        }
        // q1: c=bit10 (tid&64, wave-uniform), t=bit9 (lane bit 5)
        {
            ldmat(CMl + 1 * 4, M0, M1, M2, M3);
            if (tid & 64) {
                selmat(true, lane & 32, M0, M1, M2, M3, Mx, My);
                lane_core<32>(s, Mx, My);
            }
        }
        // q2..q6: control lane bit, target lane bit
        ldmat(CMl + 2 * 4, M0, M1, M2, M3);
        selmat(lane & 32, lane & 16, M0, M1, M2, M3, Mx, My);
        lane_core<16>(s, Mx, My);
        ldmat(CMl + 3 * 4, M0, M1, M2, M3);
        selmat(lane & 16, lane & 8, M0, M1, M2, M3, Mx, My);
        lane_core<8>(s, Mx, My);
        ldmat(CMl + 4 * 4, M0, M1, M2, M3);
        selmat(lane & 8, lane & 4, M0, M1, M2, M3, Mx, My);
        lane_core<4>(s, Mx, My);
        ldmat(CMl + 5 * 4, M0, M1, M2, M3);
        selmat(lane & 4, lane & 2, M0, M1, M2, M3, Mx, My);
        lane_core<2>(s, Mx, My);
        ldmat(CMl + 6 * 4, M0, M1, M2, M3);
        selmat(lane & 2, lane & 1, M0, M1, M2, M3, Mx, My);
        lane_core<1>(s, Mx, My);
        // q7: c=bit4 (lane bit 0), t=bit3 (local)
        {
            ldmat(CMl + 7 * 4, M0, M1, M2, M3);
            const bool c = (lane & 1) != 0;
            cplx A0 = c ? M0 : make_float2(1.f, 0.f);
            cplx A1 = c ? M1 : make_float2(0.f, 0.f);
            cplx A2 = c ? M2 : make_float2(0.f, 0.f);
            cplx A3 = c ? M3 : make_float2(1.f, 0.f);
            g1q_local<3>(s, A0, A1, A2, A3);
        }
        // q8..q10: both local
        ldmat(CMl + 8 * 4, M0, M1, M2, M3);  crot_local<3, 2>(s, M0, M1, M2, M3);
        ldmat(CMl + 9 * 4, M0, M1, M2, M3);  crot_local<2, 1>(s, M0, M1, M2, M3);
        ldmat(CMl + 10 * 4, M0, M1, M2, M3); crot_local<1, 0>(s, M0, M1, M2, M3);
        // q11: c=bit0 (local), t=bit11 (partner tid^128) — odd locals only
        {
            ldmat(CMl + 11 * 4, M0, M1, M2, M3);
            selmat(true, tid & 128, M0, M1, M2, M3, Mx, My);
            __syncthreads();
            #pragma unroll
            for (int jj = 0; jj < 8; ++jj) xbuf[jj * NT + tid] = s[2 * jj + 1];
            __syncthreads();
            #pragma unroll
            for (int jj = 0; jj < 8; ++jj) {
                cplx pv = xbuf[jj * NT + (tid ^ 128)];
                s[2 * jj + 1] = cmadd(My, pv, cmul(Mx, s[2 * jj + 1]));
            }
        }
    }

    // ---- measurement: z_q over bit (11-q); amp = (tid<<4)|j
    float psum = 0.f;
    float zl0 = 0.f, zl1 = 0.f, zl2 = 0.f, zl3 = 0.f;  // qubits 8..11 (local bits 3..0)
    #pragma unroll
    for (int j = 0; j < AMPS; ++j) {
        cplx v = s[j];
        float pr = fmaf(v.x, v.x, v.y * v.y);
        psum += pr;
        int pb = __float_as_int(pr);
        zl0 += __int_as_float(pb ^ (((j >> 3) & 1) << 31));
        zl1 += __int_as_float(pb ^ (((j >> 2) & 1) << 31));
        zl2 += __int_as_float(pb ^ (((j >> 1) & 1) << 31));
        zl3 += __int_as_float(pb ^ ((j & 1) << 31));
    }
    float zv[NQ];
    #pragma unroll
    for (int q = 0; q < 8; ++q)                         // qubits 0..7: sign = tid bit (7-q)
        zv[q] = ((tid >> (7 - q)) & 1) ? -psum : psum;
    zv[8] = zl0; zv[9] = zl1; zv[10] = zl2; zv[11] = zl3;
    #pragma unroll
    for (int q = 0; q < NQ; ++q) {
        float v = zv[q];
        #pragma unroll
        for (int off = 32; off > 0; off >>= 1) v += __shfl_xor(v, off, 64);
        zv[q] = v;
    }
    if (lane == 0) {
        const int w = tid >> 6;
        #pragma unroll
        for (int q = 0; q < NQ; ++q) zred[w][q] = zv[q];
    }
    __syncthreads();
    if (tid < NQ)
        out[(size_t)b * NQ + tid] = zred[0][tid] + zred[1][tid] + zred[2][tid] + zred[3][tid];
}

extern "C" void kernel_launch(void* const* d_in, const int* in_sizes, int n_in,
                              void* d_out, int out_size, void* d_ws, size_t ws_size,
                              hipStream_t stream) {
    const float* x     = (const float*)d_in[0];
    const float* prot  = (const float*)d_in[1];
    const float* penta = (const float*)d_in[2];
    float* out = (float*)d_out;
    const int B = in_sizes[0] / (4 * NQ);   // 4096
    qsim_kernel<<<B, NT, 0, stream>>>(x, prot, penta, out);
}

// Round 3
// 262.005 us; speedup vs baseline: 1.7297x; 1.3537x over previous
//
#include <hip/hip_runtime.h>
#include <math.h>

#define NQ   12
#define NL   4
#define NT   64
#define AMPS 64   // per-thread amplitudes (local bits [5:0]); amp = (lane<<6)|j

using cplx = float2;

__device__ __forceinline__ cplx cmul(cplx a, cplx b) {
    return make_float2(fmaf(a.x, b.x, -a.y * b.y), fmaf(a.x, b.y, a.y * b.x));
}
__device__ __forceinline__ cplx cmadd(cplx a, cplx b, cplx acc) {
    acc.x = fmaf(a.x, b.x, fmaf(-a.y, b.y, acc.x));
    acc.y = fmaf(a.x, b.y, fmaf(a.y, b.x, acc.y));
    return acc;
}
// C = A * B (2x2 complex, row-major m00 m01 m10 m11)
__device__ __forceinline__ void mm2(const cplx* A, const cplx* B, cplx* C) {
    C[0] = cmadd(A[1], B[2], cmul(A[0], B[0]));
    C[1] = cmadd(A[1], B[3], cmul(A[0], B[1]));
    C[2] = cmadd(A[3], B[2], cmul(A[2], B[0]));
    C[3] = cmadd(A[3], B[3], cmul(A[2], B[1]));
}
// PennyLane Rot(phi, theta, omega) = RZ(omega) RY(theta) RZ(phi)
__device__ __forceinline__ void rotmat(float phi, float th, float om, cplx* M) {
    float ct, st_, ca, sa, cd, sd;
    sincosf(0.5f * th, &st_, &ct);
    sincosf(0.5f * (phi + om), &sa, &ca);
    sincosf(0.5f * (phi - om), &sd, &cd);
    M[0] = make_float2(ct * ca, -ct * sa);
    M[1] = make_float2(-st_ * cd, -st_ * sd);
    M[2] = make_float2(st_ * cd, -st_ * sd);
    M[3] = make_float2(ct * ca, ct * sa);
}
// Row-select: self/partner coefficients for a pair gate given own target bit.
__device__ __forceinline__ void rowsel(const cplx* M, bool hi, cplx& Mx, cplx& My) {
    Mx = hi ? M[3] : M[0];
    My = hi ? M[2] : M[1];
}

// gate on a LANE target bit (xor mask XM), per-thread (Mx,My) already selected
template<int XM>
__device__ __forceinline__ void lane_gate(cplx* s, cplx Mx, cplx My) {
    #pragma unroll
    for (int j0 = 0; j0 < AMPS; j0 += 8) {
        cplx pv[8];
        #pragma unroll
        for (int j = 0; j < 8; ++j) {
            pv[j].x = __shfl_xor(s[j0 + j].x, XM, 64);
            pv[j].y = __shfl_xor(s[j0 + j].y, XM, 64);
        }
        #pragma unroll
        for (int j = 0; j < 8; ++j)
            s[j0 + j] = cmadd(My, pv[j], cmul(Mx, s[j0 + j]));
    }
}
// full 2x2 gate on LOCAL bit K, uniform matrix
template<int K>
__device__ __forceinline__ void local_gate(cplx* s, cplx M0, cplx M1, cplx M2, cplx M3) {
    #pragma unroll
    for (int j = 0; j < AMPS; ++j) {
        if ((j >> K) & 1) continue;
        const int i1 = j | (1 << K);
        cplx v0 = s[j], v1 = s[i1];
        s[j]  = cmadd(M1, v1, cmul(M0, v0));
        s[i1] = cmadd(M3, v1, cmul(M2, v0));
    }
}
// controlled pair-gate: control LOCAL bit CB selects A (c=0) or B (c=1), target LOCAL bit TB
template<int CB, int TB>
__device__ __forceinline__ void cgate_local(cplx* s,
    cplx A0, cplx A1, cplx A2, cplx A3,
    cplx B0, cplx B1, cplx B2, cplx B3) {
    #pragma unroll
    for (int j = 0; j < AMPS; ++j) {
        if ((j >> TB) & 1) continue;
        const int i1 = j | (1 << TB);
        cplx v0 = s[j], v1 = s[i1];
        if ((j >> CB) & 1) {
            s[j]  = cmadd(B1, v1, cmul(B0, v0));
            s[i1] = cmadd(B3, v1, cmul(B2, v0));
        } else {
            s[j]  = cmadd(A1, v1, cmul(A0, v0));
            s[i1] = cmadd(A3, v1, cmul(A2, v0));
        }
    }
}

// Wire q <-> state bit (11-q). State bit 11..6 = lane bit 5..0; bit 5..0 = local bit 5..0.
__global__ __launch_bounds__(NT, 2) void qsim_kernel(
    const float* __restrict__ x,      // (B, 4, NQ)
    const float* __restrict__ prot,   // (NL, NQ, 3)
    const float* __restrict__ penta,  // (NL, NQ, 3)
    float* __restrict__ out)          // (B, NQ)
{
    __shared__ cplx ENC[NQ][4];
    __shared__ cplx RM[NL * NQ][4];   // Rot(rot params)
    __shared__ cplx EM[NL * NQ][4];   // Rot(enta params)
    __shared__ cplx UU[NL * NQ][4];   // U_w(l) = RM * ENC
    __shared__ cplx GA[NL * NQ][4];   // controlled-gate branch c=0
    __shared__ cplx GB[NL * NQ][4];   // controlled-gate branch c=1
    __shared__ cplx ltab[AMPS];       // layer-0 product over local wires 6..11

    const int tid = threadIdx.x;      // == lane
    const int b   = blockIdx.x;

    // ---- per-sample fused encoding: ENC = RY(x3) RZ(x2) RX(x1) RY(x0)
    if (tid < NQ) {
        const int q = tid;
        const float* xb = x + (size_t)b * 4 * NQ;
        const float t0 = xb[q], t1 = xb[NQ + q], t2 = xb[2 * NQ + q], t3 = xb[3 * NQ + q];
        float c, s;
        sincosf(0.5f * t0, &s, &c);
        cplx R0[4] = {{c, 0.f}, {-s, 0.f}, {s, 0.f}, {c, 0.f}};   // RY
        sincosf(0.5f * t1, &s, &c);
        cplx R1[4] = {{c, 0.f}, {0.f, -s}, {0.f, -s}, {c, 0.f}};  // RX
        sincosf(0.5f * t2, &s, &c);
        cplx R2[4] = {{c, -s}, {0.f, 0.f}, {0.f, 0.f}, {c, s}};   // RZ
        sincosf(0.5f * t3, &s, &c);
        cplx R3[4] = {{c, 0.f}, {-s, 0.f}, {s, 0.f}, {c, 0.f}};   // RY
        cplx T1[4], T2[4], E[4];
        mm2(R1, R0, T1);
        mm2(R2, T1, T2);
        mm2(R3, T2, E);
        #pragma unroll
        for (int i = 0; i < 4; ++i) ENC[q][i] = E[i];
    }
    if (tid < NL * NQ) {
        cplx M[4];
        rotmat(prot[3 * tid], prot[3 * tid + 1], prot[3 * tid + 2], M);
        #pragma unroll
        for (int i = 0; i < 4; ++i) RM[tid][i] = M[i];
        rotmat(penta[3 * tid], penta[3 * tid + 1], penta[3 * tid + 2], M);
        #pragma unroll
        for (int i = 0; i < 4; ++i) EM[tid][i] = M[i];
    }
    __syncthreads();
    if (tid < NL * NQ) {
        cplx U[4];
        mm2(&RM[tid][0], &ENC[tid % NQ][0], U);
        #pragma unroll
        for (int i = 0; i < 4; ++i) UU[tid][i] = U[i];
    }
    __syncthreads();
    // ---- fused controlled-gate pairs.
    // q<11:  CR_q(l) absorbs U_{q+1}(l):  A = U_{q+1}(l) (I for l=0), B = EM * A
    // q==11: CR_11(l) absorbs U_0(l+1):   A = U_0(l+1)  (I for l=3), B = A * EM
    if (tid < NL * NQ) {
        const int l = tid / NQ, q = tid - l * NQ;
        cplx A[4], B[4];
        if (q < 11) {
            if (l == 0) { A[0] = {1.f,0.f}; A[1] = {0.f,0.f}; A[2] = {0.f,0.f}; A[3] = {1.f,0.f}; }
            else {
                #pragma unroll
                for (int i = 0; i < 4; ++i) A[i] = UU[l * NQ + q + 1][i];
            }
            mm2(&EM[tid][0], A, B);
        } else {
            if (l == NL - 1) { A[0] = {1.f,0.f}; A[1] = {0.f,0.f}; A[2] = {0.f,0.f}; A[3] = {1.f,0.f}; }
            else {
                #pragma unroll
                for (int i = 0; i < 4; ++i) A[i] = UU[(l + 1) * NQ][i];
            }
            mm2(A, &EM[tid][0], B);
        }
        #pragma unroll
        for (int i = 0; i < 4; ++i) { GA[tid][i] = A[i]; GB[tid][i] = B[i]; }
    }
    // ---- layer-0 1q gates on |0..0> = product state; local-wire factor table
    {
        cplx m = {1.f, 0.f};
        #pragma unroll
        for (int w = 6; w < 12; ++w) {
            const int bit = (tid >> (11 - w)) & 1;
            m = cmul(m, bit ? UU[w][2] : UU[w][0]);   // column 0 of U_w(0)
        }
        ltab[tid] = m;
    }
    __syncthreads();

    // ---- init state: s[j] = lanepref(lane) * ltab[j]
    cplx lp = {1.f, 0.f};
    #pragma unroll
    for (int w = 0; w < 6; ++w) {
        const int bit = (tid >> (5 - w)) & 1;
        lp = cmul(lp, bit ? UU[w][2] : UU[w][0]);
    }
    cplx s[AMPS];
    #pragma unroll
    for (int j = 0; j < AMPS; ++j) s[j] = cmul(lp, ltab[j]);

    // ---- 48 fused controlled-pair gates, zero barriers
    for (int l = 0; l < NL; ++l) {
        const int g = l * NQ;
        // q=0: c wire0 (lane5), t wire1 (lane4) -> xor 16
        {
            const cplx* M = ((tid >> 5) & 1) ? &GB[g + 0][0] : &GA[g + 0][0];
            cplx Mx, My; rowsel(M, (tid >> 4) & 1, Mx, My);
            lane_gate<16>(s, Mx, My);
        }
        // q=1: c lane4, t lane3 -> xor 8
        {
            const cplx* M = ((tid >> 4) & 1) ? &GB[g + 1][0] : &GA[g + 1][0];
            cplx Mx, My; rowsel(M, (tid >> 3) & 1, Mx, My);
            lane_gate<8>(s, Mx, My);
        }
        // q=2: c lane3, t lane2 -> xor 4
        {
            const cplx* M = ((tid >> 3) & 1) ? &GB[g + 2][0] : &GA[g + 2][0];
            cplx Mx, My; rowsel(M, (tid >> 2) & 1, Mx, My);
            lane_gate<4>(s, Mx, My);
        }
        // q=3: c lane2, t lane1 -> xor 2
        {
            const cplx* M = ((tid >> 2) & 1) ? &GB[g + 3][0] : &GA[g + 3][0];
            cplx Mx, My; rowsel(M, (tid >> 1) & 1, Mx, My);
            lane_gate<2>(s, Mx, My);
        }
        // q=4: c lane1, t lane0 -> xor 1
        {
            const cplx* M = ((tid >> 1) & 1) ? &GB[g + 4][0] : &GA[g + 4][0];
            cplx Mx, My; rowsel(M, tid & 1, Mx, My);
            lane_gate<1>(s, Mx, My);
        }
        // q=5: c lane0, t local bit5
        {
            const cplx* M = (tid & 1) ? &GB[g + 5][0] : &GA[g + 5][0];
            local_gate<5>(s, M[0], M[1], M[2], M[3]);
        }
        // q=6..10: control local, target local
        cgate_local<5, 4>(s, GA[g + 6][0], GA[g + 6][1], GA[g + 6][2], GA[g + 6][3],
                             GB[g + 6][0], GB[g + 6][1], GB[g + 6][2], GB[g + 6][3]);
        cgate_local<4, 3>(s, GA[g + 7][0], GA[g + 7][1], GA[g + 7][2], GA[g + 7][3],
                             GB[g + 7][0], GB[g + 7][1], GB[g + 7][2], GB[g + 7][3]);
        cgate_local<3, 2>(s, GA[g + 8][0], GA[g + 8][1], GA[g + 8][2], GA[g + 8][3],
                             GB[g + 8][0], GB[g + 8][1], GB[g + 8][2], GB[g + 8][3]);
        cgate_local<2, 1>(s, GA[g + 9][0], GA[g + 9][1], GA[g + 9][2], GA[g + 9][3],
                             GB[g + 9][0], GB[g + 9][1], GB[g + 9][2], GB[g + 9][3]);
        cgate_local<1, 0>(s, GA[g + 10][0], GA[g + 10][1], GA[g + 10][2], GA[g + 10][3],
                             GB[g + 10][0], GB[g + 10][1], GB[g + 10][2], GB[g + 10][3]);
        // q=11: c local bit0, t wire0 (lane5) -> xor 32, per-amp A/B by j parity
        {
            const bool hi = (tid >> 5) & 1;
            cplx Ax, Ay, Bx, By;
            rowsel(&GA[g + 11][0], hi, Ax, Ay);
            rowsel(&GB[g + 11][0], hi, Bx, By);
            #pragma unroll
            for (int j0 = 0; j0 < AMPS; j0 += 8) {
                cplx pv[8];
                #pragma unroll
                for (int j = 0; j < 8; ++j) {
                    pv[j].x = __shfl_xor(s[j0 + j].x, 32, 64);
                    pv[j].y = __shfl_xor(s[j0 + j].y, 32, 64);
                }
                #pragma unroll
                for (int j = 0; j < 8; ++j) {
                    if (j & 1) s[j0 + j] = cmadd(By, pv[j], cmul(Bx, s[j0 + j]));
                    else       s[j0 + j] = cmadd(Ay, pv[j], cmul(Ax, s[j0 + j]));
                }
            }
        }
    }

    // ---- measurement: z_i over state bit (11-i)
    float psum = 0.f;
    float zw6 = 0.f, zw7 = 0.f, zw8 = 0.f, zw9 = 0.f, zw10 = 0.f, zw11 = 0.f;
    #pragma unroll
    for (int j = 0; j < AMPS; ++j) {
        cplx v = s[j];
        float pr = fmaf(v.x, v.x, v.y * v.y);
        psum += pr;
        int pb = __float_as_int(pr);
        zw6  += __int_as_float(pb ^ (((j >> 5) & 1) << 31));
        zw7  += __int_as_float(pb ^ (((j >> 4) & 1) << 31));
        zw8  += __int_as_float(pb ^ (((j >> 3) & 1) << 31));
        zw9  += __int_as_float(pb ^ (((j >> 2) & 1) << 31));
        zw10 += __int_as_float(pb ^ (((j >> 1) & 1) << 31));
        zw11 += __int_as_float(pb ^ ((j & 1) << 31));
    }
    float zv[NQ];
    #pragma unroll
    for (int i = 0; i < 6; ++i)
        zv[i] = ((tid >> (5 - i)) & 1) ? -psum : psum;
    zv[6] = zw6; zv[7] = zw7; zv[8] = zw8; zv[9] = zw9; zv[10] = zw10; zv[11] = zw11;
    #pragma unroll
    for (int q = 0; q < NQ; ++q) {
        float v = zv[q];
        #pragma unroll
        for (int off = 32; off > 0; off >>= 1) v += __shfl_xor(v, off, 64);
        zv[q] = v;
    }
    if (tid == 0) {
        float* ob = out + (size_t)b * NQ;
        #pragma unroll
        for (int q = 0; q < NQ; ++q) ob[q] = zv[q];
    }
}

extern "C" void kernel_launch(void* const* d_in, const int* in_sizes, int n_in,
                              void* d_out, int out_size, void* d_ws, size_t ws_size,
                              hipStream_t stream) {
    const float* x     = (const float*)d_in[0];
    const float* prot  = (const float*)d_in[1];
    const float* penta = (const float*)d_in[2];
    float* out = (float*)d_out;
    const int B = in_sizes[0] / (4 * NQ);   // 4096
    qsim_kernel<<<B, NT, 0, stream>>>(x, prot, penta, out);
}

// Round 4
// 202.777 us; speedup vs baseline: 2.2349x; 1.2921x over previous
//
#include <hip/hip_runtime.h>
#include <math.h>

#define NQ   12
#define NL   4
#define NT   128
#define AMPS 32   // per-thread amplitudes; amp = (tid<<5) | j
// state bit 11 = tid bit 6 (wave), bits 10..5 = tid bits 5..0 (lane), bits 4..0 = j

using cplx = float2;

__device__ __forceinline__ cplx cmul(cplx a, cplx b) {
    return make_float2(fmaf(a.x, b.x, -a.y * b.y), fmaf(a.x, b.y, a.y * b.x));
}
__device__ __forceinline__ cplx cmadd(cplx a, cplx b, cplx acc) {
    acc.x = fmaf(a.x, b.x, fmaf(-a.y, b.y, acc.x));
    acc.y = fmaf(a.x, b.y, fmaf(a.y, b.x, acc.y));
    return acc;
}
// C = A * B (2x2 complex, row-major m00 m01 m10 m11)
__device__ __forceinline__ void mm2(const cplx* A, const cplx* B, cplx* C) {
    C[0] = cmadd(A[1], B[2], cmul(A[0], B[0]));
    C[1] = cmadd(A[1], B[3], cmul(A[0], B[1]));
    C[2] = cmadd(A[3], B[2], cmul(A[2], B[0]));
    C[3] = cmadd(A[3], B[3], cmul(A[2], B[1]));
}
// PennyLane Rot(phi, theta, omega) = RZ(omega) RY(theta) RZ(phi)
__device__ __forceinline__ void rotmat(float phi, float th, float om, cplx* M) {
    float ct, st_, ca, sa, cd, sd;
    sincosf(0.5f * th, &st_, &ct);
    sincosf(0.5f * (phi + om), &sa, &ca);
    sincosf(0.5f * (phi - om), &sd, &cd);
    M[0] = make_float2(ct * ca, -ct * sa);
    M[1] = make_float2(-st_ * cd, -st_ * sd);
    M[2] = make_float2(st_ * cd, -st_ * sd);
    M[3] = make_float2(ct * ca, ct * sa);
}
__device__ __forceinline__ void rowsel(const cplx* M, bool hi, cplx& Mx, cplx& My) {
    Mx = hi ? M[3] : M[0];
    My = hi ? M[2] : M[1];
}

// gate on a LANE target bit (xor mask XM); per-thread (Mx,My) pre-selected.
// 4-amp chunks to keep VGPR pressure under the 128 occupancy step.
template<int XM>
__device__ __forceinline__ void lane_gate(cplx* s, cplx Mx, cplx My) {
    #pragma unroll
    for (int j0 = 0; j0 < AMPS; j0 += 4) {
        cplx pv[4];
        #pragma unroll
        for (int j = 0; j < 4; ++j) {
            pv[j].x = __shfl_xor(s[j0 + j].x, XM, 64);
            pv[j].y = __shfl_xor(s[j0 + j].y, XM, 64);
        }
        #pragma unroll
        for (int j = 0; j < 4; ++j)
            s[j0 + j] = cmadd(My, pv[j], cmul(Mx, s[j0 + j]));
    }
}
// full 2x2 gate on LOCAL bit K, uniform matrix (per-thread)
template<int K>
__device__ __forceinline__ void local_gate(cplx* s, cplx M0, cplx M1, cplx M2, cplx M3) {
    #pragma unroll
    for (int j = 0; j < AMPS; ++j) {
        if ((j >> K) & 1) continue;
        const int i1 = j | (1 << K);
        cplx v0 = s[j], v1 = s[i1];
        s[j]  = cmadd(M1, v1, cmul(M0, v0));
        s[i1] = cmadd(M3, v1, cmul(M2, v0));
    }
}
// controlled pair-gate: control LOCAL bit CB selects A (c=0) or B (c=1), target LOCAL bit TB
template<int CB, int TB>
__device__ __forceinline__ void cgate_local(cplx* s, const cplx* A, const cplx* B) {
    cplx A0 = A[0], A1 = A[1], A2 = A[2], A3 = A[3];
    cplx B0 = B[0], B1 = B[1], B2 = B[2], B3 = B[3];
    #pragma unroll
    for (int j = 0; j < AMPS; ++j) {
        if ((j >> TB) & 1) continue;
        const int i1 = j | (1 << TB);
        cplx v0 = s[j], v1 = s[i1];
        if ((j >> CB) & 1) {
            s[j]  = cmadd(B1, v1, cmul(B0, v0));
            s[i1] = cmadd(B3, v1, cmul(B2, v0));
        } else {
            s[j]  = cmadd(A1, v1, cmul(A0, v0));
            s[i1] = cmadd(A3, v1, cmul(A2, v0));
        }
    }
}

__global__ __launch_bounds__(NT, 2) void qsim_kernel(
    const float* __restrict__ x,      // (B, 4, NQ)
    const float* __restrict__ prot,   // (NL, NQ, 3)
    const float* __restrict__ penta,  // (NL, NQ, 3)
    float* __restrict__ out)          // (B, NQ)
{
    __shared__ cplx ENC[NQ][4];
    __shared__ cplx RM[NL * NQ][4];
    __shared__ cplx EM[NL * NQ][4];
    __shared__ cplx UU[NL * NQ][4];   // U_w(l) = RM * ENC
    __shared__ cplx GA[NL * NQ][4];   // c=0 branch
    __shared__ cplx GB[NL * NQ][4];   // c=1 branch
    __shared__ cplx ltab[AMPS];       // layer-0 product over wires 7..11
    __shared__ cplx xbuf[16 * NT];    // 16 KB exchange (2 rounds of 16 amps)
    __shared__ float zred[2][NQ];

    const int tid  = threadIdx.x;
    const int lane = tid & 63;
    const int w    = tid >> 6;        // wave bit = state bit 11 = wire 0
    const int b    = blockIdx.x;

    // ---- per-sample fused encoding: ENC = RY(x3) RZ(x2) RX(x1) RY(x0)
    if (tid < NQ) {
        const int q = tid;
        const float* xb = x + (size_t)b * 4 * NQ;
        const float t0 = xb[q], t1 = xb[NQ + q], t2 = xb[2 * NQ + q], t3 = xb[3 * NQ + q];
        float c, s;
        sincosf(0.5f * t0, &s, &c);
        cplx R0[4] = {{c, 0.f}, {-s, 0.f}, {s, 0.f}, {c, 0.f}};   // RY
        sincosf(0.5f * t1, &s, &c);
        cplx R1[4] = {{c, 0.f}, {0.f, -s}, {0.f, -s}, {c, 0.f}};  // RX
        sincosf(0.5f * t2, &s, &c);
        cplx R2[4] = {{c, -s}, {0.f, 0.f}, {0.f, 0.f}, {c, s}};   // RZ
        sincosf(0.5f * t3, &s, &c);
        cplx R3[4] = {{c, 0.f}, {-s, 0.f}, {s, 0.f}, {c, 0.f}};   // RY
        cplx T1[4], T2[4], E[4];
        mm2(R1, R0, T1);
        mm2(R2, T1, T2);
        mm2(R3, T2, E);
        #pragma unroll
        for (int i = 0; i < 4; ++i) ENC[q][i] = E[i];
    }
    if (tid < NL * NQ) {
        cplx M[4];
        rotmat(prot[3 * tid], prot[3 * tid + 1], prot[3 * tid + 2], M);
        #pragma unroll
        for (int i = 0; i < 4; ++i) RM[tid][i] = M[i];
        rotmat(penta[3 * tid], penta[3 * tid + 1], penta[3 * tid + 2], M);
        #pragma unroll
        for (int i = 0; i < 4; ++i) EM[tid][i] = M[i];
    }
    __syncthreads();
    if (tid < NL * NQ) {
        cplx U[4];
        mm2(&RM[tid][0], &ENC[tid % NQ][0], U);
        #pragma unroll
        for (int i = 0; i < 4; ++i) UU[tid][i] = U[i];
    }
    __syncthreads();
    // ---- fused controlled-gate pairs (validated in round 3):
    // q<11:  A = U_{q+1}(l) (I for l=0), B = EM * A
    // q==11: A = U_0(l+1)   (I for l=3), B = A * EM
    if (tid < NL * NQ) {
        const int l = tid / NQ, q = tid - l * NQ;
        cplx A[4], B[4];
        if (q < 11) {
            if (l == 0) { A[0] = {1.f,0.f}; A[1] = {0.f,0.f}; A[2] = {0.f,0.f}; A[3] = {1.f,0.f}; }
            else {
                #pragma unroll
                for (int i = 0; i < 4; ++i) A[i] = UU[l * NQ + q + 1][i];
            }
            mm2(&EM[tid][0], A, B);
        } else {
            if (l == NL - 1) { A[0] = {1.f,0.f}; A[1] = {0.f,0.f}; A[2] = {0.f,0.f}; A[3] = {1.f,0.f}; }
            else {
                #pragma unroll
                for (int i = 0; i < 4; ++i) A[i] = UU[(l + 1) * NQ][i];
            }
            mm2(A, &EM[tid][0], B);
        }
        #pragma unroll
        for (int i = 0; i < 4; ++i) { GA[tid][i] = A[i]; GB[tid][i] = B[i]; }
    }
    // ---- layer-0 local-wire product table (wires 7..11 -> j bits 4..0)
    if (tid >= 64 && tid < 64 + AMPS) {
        const int j = tid - 64;
        cplx m = {1.f, 0.f};
        #pragma unroll
        for (int wq = 7; wq < 12; ++wq) {
            const int bit = (j >> (11 - wq)) & 1;
            m = cmul(m, bit ? UU[wq][2] : UU[wq][0]);
        }
        ltab[j] = m;
    }
    __syncthreads();

    // ---- init: product state from layer-0 1q gates
    cplx lp = {1.f, 0.f};
    #pragma unroll
    for (int wq = 0; wq < 7; ++wq) {
        const int bit = (tid >> (6 - wq)) & 1;
        lp = cmul(lp, bit ? UU[wq][2] : UU[wq][0]);
    }
    cplx s[AMPS];
    #pragma unroll
    for (int j = 0; j < AMPS; ++j) s[j] = cmul(lp, ltab[j]);

    // ---- 48 fused controlled-pair gates
    for (int l = 0; l < NL; ++l) {
        const int g = l * NQ;
        // q=0: c wire0 (wave bit, wave-uniform), t wire1 = lane bit5 (xor 32)
        {
            const cplx* M = w ? &GB[g + 0][0] : &GA[g + 0][0];
            cplx Mx, My; rowsel(M, (tid >> 5) & 1, Mx, My);
            lane_gate<32>(s, Mx, My);
        }
        // q=1: c lane5, t lane4 (xor 16)
        {
            const cplx* M = ((tid >> 5) & 1) ? &GB[g + 1][0] : &GA[g + 1][0];
            cplx Mx, My; rowsel(M, (tid >> 4) & 1, Mx, My);
            lane_gate<16>(s, Mx, My);
        }
        // q=2: c lane4, t lane3 (xor 8)
        {
            const cplx* M = ((tid >> 4) & 1) ? &GB[g + 2][0] : &GA[g + 2][0];
            cplx Mx, My; rowsel(M, (tid >> 3) & 1, Mx, My);
            lane_gate<8>(s, Mx, My);
        }
        // q=3: c lane3, t lane2 (xor 4)
        {
            const cplx* M = ((tid >> 3) & 1) ? &GB[g + 3][0] : &GA[g + 3][0];
            cplx Mx, My; rowsel(M, (tid >> 2) & 1, Mx, My);
            lane_gate<4>(s, Mx, My);
        }
        // q=4: c lane2, t lane1 (xor 2)
        {
            const cplx* M = ((tid >> 2) & 1) ? &GB[g + 4][0] : &GA[g + 4][0];
            cplx Mx, My; rowsel(M, (tid >> 1) & 1, Mx, My);
            lane_gate<2>(s, Mx, My);
        }
        // q=5: c lane1, t lane0 (xor 1)
        {
            const cplx* M = ((tid >> 1) & 1) ? &GB[g + 5][0] : &GA[g + 5][0];
            cplx Mx, My; rowsel(M, tid & 1, Mx, My);
            lane_gate<1>(s, Mx, My);
        }
        // q=6: c lane0, t local bit4
        {
            const cplx* M = (tid & 1) ? &GB[g + 6][0] : &GA[g + 6][0];
            local_gate<4>(s, M[0], M[1], M[2], M[3]);
        }
        // q=7..10: both local
        cgate_local<4, 3>(s, &GA[g + 7][0], &GB[g + 7][0]);
        cgate_local<3, 2>(s, &GA[g + 8][0], &GB[g + 8][0]);
        cgate_local<2, 1>(s, &GA[g + 9][0], &GB[g + 9][0]);
        cgate_local<1, 0>(s, &GA[g + 10][0], &GB[g + 10][0]);
        // q=11: c local bit0 (j parity), t wire0 = wave bit -> LDS exchange with tid^64
        {
            cplx Ax, Ay, Bx, By;
            rowsel(&GA[g + 11][0], w, Ax, Ay);
            rowsel(&GB[g + 11][0], w, Bx, By);
            #pragma unroll
            for (int r = 0; r < 2; ++r) {
                __syncthreads();
                #pragma unroll
                for (int j2 = 0; j2 < 16; ++j2) xbuf[j2 * NT + tid] = s[r * 16 + j2];
                __syncthreads();
                #pragma unroll
                for (int j2 = 0; j2 < 16; ++j2) {
                    cplx pv = xbuf[j2 * NT + (tid ^ 64)];
                    const int j = r * 16 + j2;
                    if (j & 1) s[j] = cmadd(By, pv, cmul(Bx, s[j]));
                    else       s[j] = cmadd(Ay, pv, cmul(Ax, s[j]));
                }
            }
        }
    }

    // ---- measurement
    float psum = 0.f;
    float zl0 = 0.f, zl1 = 0.f, zl2 = 0.f, zl3 = 0.f, zl4 = 0.f;  // wires 7..11
    #pragma unroll
    for (int j = 0; j < AMPS; ++j) {
        cplx v = s[j];
        float pr = fmaf(v.x, v.x, v.y * v.y);
        psum += pr;
        int pb = __float_as_int(pr);
        zl0 += __int_as_float(pb ^ (((j >> 4) & 1) << 31));
        zl1 += __int_as_float(pb ^ (((j >> 3) & 1) << 31));
        zl2 += __int_as_float(pb ^ (((j >> 2) & 1) << 31));
        zl3 += __int_as_float(pb ^ (((j >> 1) & 1) << 31));
        zl4 += __int_as_float(pb ^ ((j & 1) << 31));
    }
    float zv[NQ];
    #pragma unroll
    for (int i = 0; i < 7; ++i)                       // wires 0..6: sign = tid bit (6-i)
        zv[i] = ((tid >> (6 - i)) & 1) ? -psum : psum;
    zv[7] = zl0; zv[8] = zl1; zv[9] = zl2; zv[10] = zl3; zv[11] = zl4;
    #pragma unroll
    for (int q = 0; q < NQ; ++q) {
        float v = zv[q];
        #pragma unroll
        for (int off = 32; off > 0; off >>= 1) v += __shfl_xor(v, off, 64);
        zv[q] = v;
    }
    if (lane == 0) {
        #pragma unroll
        for (int q = 0; q < NQ; ++q) zred[w][q] = zv[q];
    }
    __syncthreads();
    if (tid < NQ)
        out[(size_t)b * NQ + tid] = zred[0][tid] + zred[1][tid];
}

extern "C" void kernel_launch(void* const* d_in, const int* in_sizes, int n_in,
                              void* d_out, int out_size, void* d_ws, size_t ws_size,
                              hipStream_t stream) {
    const float* x     = (const float*)d_in[0];
    const float* prot  = (const float*)d_in[1];
    const float* penta = (const float*)d_in[2];
    float* out = (float*)d_out;
    const int B = in_sizes[0] / (4 * NQ);   // 4096
    qsim_kernel<<<B, NT, 0, stream>>>(x, prot, penta, out);
}